// Round 7
// baseline (190.900 us; speedup 1.0000x reference)
//
#include <hip/hip_runtime.h>
#include <hip/hip_bf16.h>
#include <cstdint>

#define B_SZ   2
#define S_LEN  2048
#define NH     16
#define NT     32   // number of 64-row q-tiles per (b,h)
#define LDA    72   // attention LDS stride (bf16): 144B rows -> 16B aligned

using f32x4 = __attribute__((ext_vector_type(4))) float;
typedef __bf16 bf16x8 __attribute__((ext_vector_type(8)));
typedef __bf16 bf16x4 __attribute__((ext_vector_type(4)));

__device__ inline float bf2f(unsigned short u) {
    union { unsigned int i; float f; } v; v.i = ((unsigned int)u) << 16; return v.f;
}
__device__ inline unsigned short f2bf(float f) {
    union { float f; unsigned int i; } v; v.f = f;
    unsigned int r = v.i + 0x7fff + ((v.i >> 16) & 1);
    return (unsigned short)(r >> 16);
}
__device__ inline f32x4 mfma16(bf16x8 a, bf16x8 b, f32x4 c) {
    return __builtin_amdgcn_mfma_f32_16x16x32_bf16(a, b, c, 0, 0, 0);
}
__device__ inline void stC(float* C, size_t idx, float v)  { C[idx] = v; }
__device__ inline void stC(__bf16* C, size_t idx, float v) { ((unsigned short*)C)[idx] = f2bf(v); }

// fp32 -> bf16, two regions in one launch
__global__ __launch_bounds__(256) void f2b2_kernel(
    const float* __restrict__ a, int na4, __bf16* __restrict__ outa,
    const float* __restrict__ b, int nb4, __bf16* __restrict__ outb)
{
    int i = blockIdx.x * blockDim.x + threadIdx.x;
    const float* src; __bf16* dst; int idx;
    if (i < na4)           { src = a; dst = outa; idx = i; }
    else if (i < na4 + nb4){ src = b; dst = outb; idx = i - na4; }
    else return;
    float4 v = ((const float4*)src)[idx];
    ushort4 o;
    o.x = f2bf(v.x); o.y = f2bf(v.y); o.z = f2bf(v.z); o.w = f2bf(v.w);
    ((ushort4*)dst)[idx] = o;
}

__global__ __launch_bounds__(256) void f2b_kernel(
    const float* __restrict__ in, __bf16* __restrict__ out, int n4)
{
    int i = blockIdx.x * blockDim.x + threadIdx.x;
    if (i < n4) {
        float4 v = ((const float4*)in)[i];
        ushort4 o;
        o.x = f2bf(v.x); o.y = f2bf(v.y); o.z = f2bf(v.z); o.w = f2bf(v.w);
        ((ushort4*)out)[i] = o;
    }
}

// C[M,N] = A[M,K] @ W[N,K]^T. 128x128 tile, BK=32, global_load_lds 16B staging,
// XOR-swizzled k-segments, double-buffered (one barrier per K-iter).
template <typename TO, int HAS_BIAS>
__global__ __launch_bounds__(256) void gemm128(
    const __bf16* __restrict__ A, const __bf16* __restrict__ W,
    const float* __restrict__ bias, TO* __restrict__ C,
    int M, int N, int K)
{
    __shared__ __bf16 Alds[2][128 * 32];
    __shared__ __bf16 Blds[2][128 * 32];
    const int tid  = threadIdx.x, lane = tid & 63, w = tid >> 6;
    const int c16  = lane & 15, quad = lane >> 4;
    const int mBase = blockIdx.y * 128, nBase = blockIdx.x * 128;
    const int moff = (w & 1) * 64, noff = (w >> 1) * 64;

    f32x4 acc[4][4];
#pragma unroll
    for (int i = 0; i < 4; ++i)
#pragma unroll
        for (int j = 0; j < 4; ++j) acc[i][j] = (f32x4){0.f, 0.f, 0.f, 0.f};

    auto stage = [&](int buf, int k0) {
#pragma unroll
        for (int p = 0; p < 2; ++p) {
            const int linear = p * 256 + tid;
            const int row = linear >> 2;
            const int seg = (linear & 3) ^ (row & 3);
            const int lbase = (p * 256 + w * 64) * 8;
            const __bf16* ga = A + (size_t)(mBase + row) * K + k0 + seg * 8;
            const __bf16* gb = W + (size_t)(nBase + row) * K + k0 + seg * 8;
            __builtin_amdgcn_global_load_lds(
                (const __attribute__((address_space(1))) void*)ga,
                (__attribute__((address_space(3))) void*)(&Alds[buf][lbase]), 16, 0, 0);
            __builtin_amdgcn_global_load_lds(
                (const __attribute__((address_space(1))) void*)gb,
                (__attribute__((address_space(3))) void*)(&Blds[buf][lbase]), 16, 0, 0);
        }
    };

    stage(0, 0);
    int cur = 0;
    for (int k0 = 0; k0 < K; k0 += 32) {
        __syncthreads();
        if (k0 + 32 < K) stage(cur ^ 1, k0 + 32);

        bf16x8 af[4], bw[4];
#pragma unroll
        for (int i = 0; i < 4; ++i) {
            const int rowA = moff + i * 16 + c16;
            af[i] = *(const bf16x8*)&Alds[cur][rowA * 32 + ((quad ^ (rowA & 3)) << 3)];
            const int rowB = noff + i * 16 + c16;
            bw[i] = *(const bf16x8*)&Blds[cur][rowB * 32 + ((quad ^ (rowB & 3)) << 3)];
        }
#pragma unroll
        for (int i = 0; i < 4; ++i)
#pragma unroll
            for (int j = 0; j < 4; ++j)
                acc[i][j] = mfma16(af[i], bw[j], acc[i][j]);
        cur ^= 1;
    }

#pragma unroll
    for (int j = 0; j < 4; ++j) {
        const int col = nBase + noff + j * 16 + c16;
        const float bv = HAS_BIAS ? bias[col] : 0.f;
#pragma unroll
        for (int i = 0; i < 4; ++i)
#pragma unroll
            for (int r = 0; r < 4; ++r) {
                const int row = mBase + moff + i * 16 + quad * 4 + r;
                stC(C, (size_t)row * N + col, acc[i][j][r] + bv);
            }
    }
}

// 64x128 tile variant (BM=64): grid doubles -> 2 blocks/CU for the small proj GEMM.
// Wave tile 32(M)x64(N), 8 MFMAs/iter.
template <typename TO, int HAS_BIAS>
__global__ __launch_bounds__(256) void gemm64(
    const __bf16* __restrict__ A, const __bf16* __restrict__ W,
    const float* __restrict__ bias, TO* __restrict__ C,
    int M, int N, int K)
{
    __shared__ __bf16 Alds[2][64 * 32];
    __shared__ __bf16 Blds[2][128 * 32];
    const int tid  = threadIdx.x, lane = tid & 63, w = tid >> 6;
    const int c16  = lane & 15, quad = lane >> 4;
    const int mBase = blockIdx.y * 64, nBase = blockIdx.x * 128;
    const int moff = (w & 1) * 32, noff = (w >> 1) * 64;

    f32x4 acc[2][4];
#pragma unroll
    for (int i = 0; i < 2; ++i)
#pragma unroll
        for (int j = 0; j < 4; ++j) acc[i][j] = (f32x4){0.f, 0.f, 0.f, 0.f};

    auto stage = [&](int buf, int k0) {
        {   // A: 64 rows x 32 -> one 16B load per thread
            const int row = tid >> 2;
            const int seg = (tid & 3) ^ (row & 3);
            const int lbase = (w * 64) * 8;
            const __bf16* ga = A + (size_t)(mBase + row) * K + k0 + seg * 8;
            __builtin_amdgcn_global_load_lds(
                (const __attribute__((address_space(1))) void*)ga,
                (__attribute__((address_space(3))) void*)(&Alds[buf][lbase]), 16, 0, 0);
        }
#pragma unroll
        for (int p = 0; p < 2; ++p) {  // B: 128 rows x 32
            const int linear = p * 256 + tid;
            const int row = linear >> 2;
            const int seg = (linear & 3) ^ (row & 3);
            const int lbase = (p * 256 + w * 64) * 8;
            const __bf16* gb = W + (size_t)(nBase + row) * K + k0 + seg * 8;
            __builtin_amdgcn_global_load_lds(
                (const __attribute__((address_space(1))) void*)gb,
                (__attribute__((address_space(3))) void*)(&Blds[buf][lbase]), 16, 0, 0);
        }
    };

    stage(0, 0);
    int cur = 0;
    for (int k0 = 0; k0 < K; k0 += 32) {
        __syncthreads();
        if (k0 + 32 < K) stage(cur ^ 1, k0 + 32);

        bf16x8 af[2], bw[4];
#pragma unroll
        for (int i = 0; i < 2; ++i) {
            const int rowA = moff + i * 16 + c16;
            af[i] = *(const bf16x8*)&Alds[cur][rowA * 32 + ((quad ^ (rowA & 3)) << 3)];
        }
#pragma unroll
        for (int j = 0; j < 4; ++j) {
            const int rowB = noff + j * 16 + c16;
            bw[j] = *(const bf16x8*)&Blds[cur][rowB * 32 + ((quad ^ (rowB & 3)) << 3)];
        }
#pragma unroll
        for (int i = 0; i < 2; ++i)
#pragma unroll
            for (int j = 0; j < 4; ++j)
                acc[i][j] = mfma16(af[i], bw[j], acc[i][j]);
        cur ^= 1;
    }

#pragma unroll
    for (int j = 0; j < 4; ++j) {
        const int col = nBase + noff + j * 16 + c16;
        const float bv = HAS_BIAS ? bias[col] : 0.f;
#pragma unroll
        for (int i = 0; i < 2; ++i)
#pragma unroll
            for (int r = 0; r < 4; ++r) {
                const int row = mBase + moff + i * 16 + quad * 4 + r;
                stC(C, (size_t)row * N + col, acc[i][j][r] + bv);
            }
    }
}

// One 64-query flash tile of one (b,h): stage Q, loop causal key chunks, store O.
// Fixed-reference softmax (m=0, exp2 domain); key-permutation k'=c16*4+j for
// packed P/V LDS writes; straight-line register prefetch of next chunk's K/V.
__device__ __forceinline__ void attn_tile(
    const __bf16* __restrict__ qkv, __bf16* __restrict__ ctx,
    int b, int h, int qt, int tid,
    __bf16* Qs, __bf16* Ks, __bf16* Vs, __bf16* Ps)
{
    const int lane = tid & 63;
    const int w    = tid >> 6;
    const int c16  = lane & 15;
    const int quad = lane >> 4;
    const int qBase = qt * 64;

    const float QS = 0.125f * 1.4426950408889634f;  // (1/sqrt(64)) * log2(e)

    const int krow0 = tid >> 3;
    const int kd0   = (tid & 7) * 8;
    const int c16t = tid & 15;
    const int jh   = (tid >> 4) & 1;
    const int dblk = tid >> 5;

    const size_t rowB = (size_t)b * S_LEN;
    const __bf16* kp0 = qkv + (rowB + krow0) * 3072 + 1024 + h * 64 + kd0;
    const __bf16* kp1 = kp0 + (size_t)32 * 3072;
    const __bf16* vp0 = qkv + (rowB + 2 * jh * 16 + c16t) * 3072 + 2048 + h * 64 + dblk * 8;
    const __bf16* vp1 = vp0 + (size_t)16 * 3072;

    uint4 kr0 = *(const uint4*)kp0;
    uint4 kr1 = *(const uint4*)kp1;
    uint4 vr0 = *(const uint4*)vp0;
    uint4 vr1 = *(const uint4*)vp1;

    // stage Q (scaled)
#pragma unroll
    for (int p = 0; p < 2; ++p) {
        const int linear = p * 256 + tid;
        const int row = linear >> 3;
        const int d0 = (linear & 7) * 8;
        const __bf16* g = qkv + (rowB + qBase + row) * 3072 + h * 64 + d0;
        uint4 raw = *(const uint4*)g;
        const unsigned short* u = (const unsigned short*)&raw;
        unsigned short tmp[8];
#pragma unroll
        for (int jj = 0; jj < 8; ++jj) tmp[jj] = f2bf(bf2f(u[jj]) * QS);
        *(uint4*)&Qs[row * LDA + d0] = *(const uint4*)tmp;
    }
    __syncthreads();

    const bf16x8 aq0 = *(const bf16x8*)&Qs[(w * 16 + c16) * LDA + quad * 8];
    const bf16x8 aq1 = *(const bf16x8*)&Qs[(w * 16 + c16) * LDA + 32 + quad * 8];

    float l_r[4] = {0.f, 0.f, 0.f, 0.f};
    f32x4 acc_o[4];
#pragma unroll
    for (int j = 0; j < 4; ++j) acc_o[j] = (f32x4){0.f, 0.f, 0.f, 0.f};

    const int nCh = qt + 1;
    for (int cc = 0; cc < nCh; ++cc) {
        *(uint4*)&Ks[krow0 * LDA + kd0]        = kr0;
        *(uint4*)&Ks[(krow0 + 32) * LDA + kd0] = kr1;
        {
            const unsigned short* e1 = (const unsigned short*)&vr0;
            const unsigned short* e2 = (const unsigned short*)&vr1;
#pragma unroll
            for (int d = 0; d < 8; ++d) {
                const unsigned pack = (unsigned)e1[d] | ((unsigned)e2[d] << 16);
                *(unsigned*)&Vs[(dblk * 8 + d) * LDA + c16t * 4 + 2 * jh] = pack;
            }
        }
        __syncthreads();

        if (cc + 1 < nCh) {
            kp0 += (size_t)64 * 3072; kp1 += (size_t)64 * 3072;
            vp0 += (size_t)64 * 3072; vp1 += (size_t)64 * 3072;
            kr0 = *(const uint4*)kp0;
            kr1 = *(const uint4*)kp1;
            vr0 = *(const uint4*)vp0;
            vr1 = *(const uint4*)vp1;
        }

        f32x4 sc[4];
#pragma unroll
        for (int j = 0; j < 4; ++j) sc[j] = (f32x4){0.f, 0.f, 0.f, 0.f};
#pragma unroll
        for (int j = 0; j < 4; ++j) {
            bf16x8 bk0 = *(const bf16x8*)&Ks[(j * 16 + c16) * LDA + quad * 8];
            bf16x8 bk1 = *(const bf16x8*)&Ks[(j * 16 + c16) * LDA + 32 + quad * 8];
            sc[j] = mfma16(aq0, bk0, sc[j]);
            sc[j] = mfma16(aq1, bk1, sc[j]);
        }

        if (cc == nCh - 1) {
#pragma unroll
            for (int j = 0; j < 4; ++j) {
                const int key = cc * 64 + j * 16 + c16;
#pragma unroll
                for (int r = 0; r < 4; ++r) {
                    const int q = qBase + w * 16 + quad * 4 + r;
                    if (key > q) sc[j][r] = -1e30f;
                }
            }
        }

        float p_[4][4];
#pragma unroll
        for (int j = 0; j < 4; ++j)
#pragma unroll
            for (int r = 0; r < 4; ++r)
                p_[j][r] = exp2f(sc[j][r]);
#pragma unroll
        for (int r = 0; r < 4; ++r)
            l_r[r] += (p_[0][r] + p_[1][r]) + (p_[2][r] + p_[3][r]);

#pragma unroll
        for (int r = 0; r < 4; ++r) {
            bf16x4 pb;
            pb[0] = (__bf16)p_[0][r]; pb[1] = (__bf16)p_[1][r];
            pb[2] = (__bf16)p_[2][r]; pb[3] = (__bf16)p_[3][r];
            *(bf16x4*)&Ps[(w * 16 + quad * 4 + r) * LDA + c16 * 4] = pb;
        }

        bf16x8 ap0 = *(const bf16x8*)&Ps[(w * 16 + c16) * LDA + quad * 8];
        bf16x8 ap1 = *(const bf16x8*)&Ps[(w * 16 + c16) * LDA + 32 + quad * 8];
#pragma unroll
        for (int j = 0; j < 4; ++j) {
            bf16x8 bv0 = *(const bf16x8*)&Vs[(j * 16 + c16) * LDA + quad * 8];
            bf16x8 bv1 = *(const bf16x8*)&Vs[(j * 16 + c16) * LDA + 32 + quad * 8];
            acc_o[j] = mfma16(ap0, bv0, acc_o[j]);
            acc_o[j] = mfma16(ap1, bv1, acc_o[j]);
        }
        __syncthreads();
    }

#pragma unroll
    for (int r = 0; r < 4; ++r) {
        float l = l_r[r];
        l += __shfl_xor(l, 1);
        l += __shfl_xor(l, 2);
        l += __shfl_xor(l, 4);
        l += __shfl_xor(l, 8);
        const float inv = 1.0f / l;
        const size_t rowO = (rowB + qBase + w * 16 + quad * 4 + r) * 1024 + h * 64;
#pragma unroll
        for (int j = 0; j < 4; ++j)
            ctx[rowO + j * 16 + c16] = (__bf16)(acc_o[j][r] * inv);
    }
}

// Balanced pairing: block y handles q-tiles (NT-1-y) and (y) -> every block
// does exactly NT+1 chunk-iters (uniform duration, no lone-block tail).
__global__ __launch_bounds__(256) void attn(
    const __bf16* __restrict__ qkv, __bf16* __restrict__ ctx)
{
    __shared__ __bf16 Qs[64 * LDA];
    __shared__ __bf16 Ks[64 * LDA];
    __shared__ __bf16 Vs[64 * LDA];
    __shared__ __bf16 Ps[64 * LDA];

    const int bh = blockIdx.x, b = bh >> 4, h = bh & 15;
    const int y  = blockIdx.y;

    attn_tile(qkv, ctx, b, h, NT - 1 - y, threadIdx.x, Qs, Ks, Vs, Ps);
    attn_tile(qkv, ctx, b, h, y,          threadIdx.x, Qs, Ks, Vs, Ps);
}

extern "C" void kernel_launch(void* const* d_in, const int* in_sizes, int n_in,
                              void* d_out, int out_size, void* d_ws, size_t ws_size,
                              hipStream_t stream) {
    const float* x      = (const float*)d_in[0];  // [2,2048,1024]
    const float* w_qkv  = (const float*)d_in[1];  // [3072,1024]
    const float* w_proj = (const float*)d_in[2];  // [1024,1024]
    const float* b_proj = (const float*)d_in[3];  // [1024]
    float* out = (float*)d_out;

    // workspace layout (40 MB peak; lifetimes serial on `stream`)
    __bf16* qkvb = (__bf16*)d_ws;                         // [4096,3072]  25.2 MB
    __bf16* xb   = qkvb + (size_t)4096 * 3072;            // [4096,1024]   8.4 MB
    __bf16* wqb  = xb + (size_t)4096 * 1024;              // [3072,1024]   6.3 MB
    __bf16* ctxb = xb;    // reuses xb (dead after QKV GEMM)
    __bf16* wpb  = wqb;   // reuses wqb (dead after QKV GEMM)

    const int M = B_SZ * S_LEN;  // 4096
    const int nx4 = 4096 * 1024 / 4, nq4 = 3072 * 1024 / 4, np4 = 1024 * 1024 / 4;

    // convert x + w_qkv to bf16 (single launch)
    f2b2_kernel<<<(nx4 + nq4 + 255) / 256, 256, 0, stream>>>(x, nx4, xb, w_qkv, nq4, wqb);

    // 1) QKV projection -> bf16 (128x128 tiles, 768 blocks = 3/CU)
    gemm128<__bf16, 0><<<dim3(3072 / 128, M / 128), 256, 0, stream>>>(
        xb, wqb, nullptr, qkvb, M, 3072, 1024);

    // convert proj weights (wqb dead now; runs before attn to shrink the critical gap)
    f2b_kernel<<<(np4 + 255) / 256, 256, 0, stream>>>(w_proj, wpb, np4);

    // 2) causal flash attention, balanced q-tile pairs (512 blocks = 2/CU)
    attn<<<dim3(B_SZ * NH, NT / 2), 256, 0, stream>>>(qkvb, ctxb);

    // 3) output projection + bias -> fp32 (64x128 tiles, 512 blocks = 2/CU)
    gemm64<float, 1><<<dim3(1024 / 128, M / 64), 256, 0, stream>>>(
        ctxb, wpb, b_proj, out, M, 1024, 1024);
}

// Round 8
// 184.922 us; speedup vs baseline: 1.0323x; 1.0323x over previous
//
#include <hip/hip_runtime.h>
#include <hip/hip_bf16.h>
#include <cstdint>

#define B_SZ   2
#define S_LEN  2048
#define NH     16
#define NT     32   // 64-row q-tiles per (b,h)
#define LDA    72   // attention LDS stride (bf16): 144B rows -> 16B aligned

using f32x4 = __attribute__((ext_vector_type(4))) float;
typedef __bf16 bf16x8 __attribute__((ext_vector_type(8)));
typedef __bf16 bf16x4 __attribute__((ext_vector_type(4)));

__device__ inline float bf2f(unsigned short u) {
    union { unsigned int i; float f; } v; v.i = ((unsigned int)u) << 16; return v.f;
}
__device__ inline unsigned short f2bf(float f) {
    union { float f; unsigned int i; } v; v.f = f;
    unsigned int r = v.i + 0x7fff + ((v.i >> 16) & 1);
    return (unsigned short)(r >> 16);
}
__device__ inline f32x4 mfma16(bf16x8 a, bf16x8 b, f32x4 c) {
    return __builtin_amdgcn_mfma_f32_16x16x32_bf16(a, b, c, 0, 0, 0);
}
__device__ inline void stC(float* C, size_t idx, float v)  { C[idx] = v; }
__device__ inline void stC(__bf16* C, size_t idx, float v) { ((unsigned short*)C)[idx] = f2bf(v); }

// fp32 -> bf16, two regions in one launch
__global__ __launch_bounds__(256) void f2b2_kernel(
    const float* __restrict__ a, int na4, __bf16* __restrict__ outa,
    const float* __restrict__ b, int nb4, __bf16* __restrict__ outb)
{
    int i = blockIdx.x * blockDim.x + threadIdx.x;
    const float* src; __bf16* dst; int idx;
    if (i < na4)           { src = a; dst = outa; idx = i; }
    else if (i < na4 + nb4){ src = b; dst = outb; idx = i - na4; }
    else return;
    float4 v = ((const float4*)src)[idx];
    ushort4 o;
    o.x = f2bf(v.x); o.y = f2bf(v.y); o.z = f2bf(v.z); o.w = f2bf(v.w);
    ((ushort4*)dst)[idx] = o;
}

__global__ __launch_bounds__(256) void f2b_kernel(
    const float* __restrict__ in, __bf16* __restrict__ out, int n4)
{
    int i = blockIdx.x * blockDim.x + threadIdx.x;
    if (i < n4) {
        float4 v = ((const float4*)in)[i];
        ushort4 o;
        o.x = f2bf(v.x); o.y = f2bf(v.y); o.z = f2bf(v.z); o.w = f2bf(v.w);
        ((ushort4*)out)[i] = o;
    }
}

// C[M,N] = A[M,K] @ W[N,K]^T. 128x128 tile, BK=32, global_load_lds 16B staging,
// XOR-swizzled k-segments, double-buffered (one barrier per K-iter).
template <typename TO, int HAS_BIAS>
__global__ __launch_bounds__(256) void gemm128(
    const __bf16* __restrict__ A, const __bf16* __restrict__ W,
    const float* __restrict__ bias, TO* __restrict__ C,
    int M, int N, int K)
{
    __shared__ __bf16 Alds[2][128 * 32];
    __shared__ __bf16 Blds[2][128 * 32];
    const int tid  = threadIdx.x, lane = tid & 63, w = tid >> 6;
    const int c16  = lane & 15, quad = lane >> 4;
    const int mBase = blockIdx.y * 128, nBase = blockIdx.x * 128;
    const int moff = (w & 1) * 64, noff = (w >> 1) * 64;

    f32x4 acc[4][4];
#pragma unroll
    for (int i = 0; i < 4; ++i)
#pragma unroll
        for (int j = 0; j < 4; ++j) acc[i][j] = (f32x4){0.f, 0.f, 0.f, 0.f};

    auto stage = [&](int buf, int k0) {
#pragma unroll
        for (int p = 0; p < 2; ++p) {
            const int linear = p * 256 + tid;
            const int row = linear >> 2;
            const int seg = (linear & 3) ^ (row & 3);
            const int lbase = (p * 256 + w * 64) * 8;
            const __bf16* ga = A + (size_t)(mBase + row) * K + k0 + seg * 8;
            const __bf16* gb = W + (size_t)(nBase + row) * K + k0 + seg * 8;
            __builtin_amdgcn_global_load_lds(
                (const __attribute__((address_space(1))) void*)ga,
                (__attribute__((address_space(3))) void*)(&Alds[buf][lbase]), 16, 0, 0);
            __builtin_amdgcn_global_load_lds(
                (const __attribute__((address_space(1))) void*)gb,
                (__attribute__((address_space(3))) void*)(&Blds[buf][lbase]), 16, 0, 0);
        }
    };

    stage(0, 0);
    int cur = 0;
    for (int k0 = 0; k0 < K; k0 += 32) {
        __syncthreads();
        if (k0 + 32 < K) stage(cur ^ 1, k0 + 32);

        bf16x8 af[4], bw[4];
#pragma unroll
        for (int i = 0; i < 4; ++i) {
            const int rowA = moff + i * 16 + c16;
            af[i] = *(const bf16x8*)&Alds[cur][rowA * 32 + ((quad ^ (rowA & 3)) << 3)];
            const int rowB = noff + i * 16 + c16;
            bw[i] = *(const bf16x8*)&Blds[cur][rowB * 32 + ((quad ^ (rowB & 3)) << 3)];
        }
#pragma unroll
        for (int i = 0; i < 4; ++i)
#pragma unroll
            for (int j = 0; j < 4; ++j)
                acc[i][j] = mfma16(af[i], bw[j], acc[i][j]);
        cur ^= 1;
    }

#pragma unroll
    for (int j = 0; j < 4; ++j) {
        const int col = nBase + noff + j * 16 + c16;
        const float bv = HAS_BIAS ? bias[col] : 0.f;
#pragma unroll
        for (int i = 0; i < 4; ++i)
#pragma unroll
            for (int r = 0; r < 4; ++r) {
                const int row = mBase + moff + i * 16 + quad * 4 + r;
                stC(C, (size_t)row * N + col, acc[i][j][r] + bv);
            }
    }
}

// 64x128 tile variant (BM=64): 2 blocks/CU for the small proj GEMM.
template <typename TO, int HAS_BIAS>
__global__ __launch_bounds__(256) void gemm64(
    const __bf16* __restrict__ A, const __bf16* __restrict__ W,
    const float* __restrict__ bias, TO* __restrict__ C,
    int M, int N, int K)
{
    __shared__ __bf16 Alds[2][64 * 32];
    __shared__ __bf16 Blds[2][128 * 32];
    const int tid  = threadIdx.x, lane = tid & 63, w = tid >> 6;
    const int c16  = lane & 15, quad = lane >> 4;
    const int mBase = blockIdx.y * 64, nBase = blockIdx.x * 128;
    const int moff = (w & 1) * 32, noff = (w >> 1) * 64;

    f32x4 acc[2][4];
#pragma unroll
    for (int i = 0; i < 2; ++i)
#pragma unroll
        for (int j = 0; j < 4; ++j) acc[i][j] = (f32x4){0.f, 0.f, 0.f, 0.f};

    auto stage = [&](int buf, int k0) {
        {
            const int row = tid >> 2;
            const int seg = (tid & 3) ^ (row & 3);
            const int lbase = (w * 64) * 8;
            const __bf16* ga = A + (size_t)(mBase + row) * K + k0 + seg * 8;
            __builtin_amdgcn_global_load_lds(
                (const __attribute__((address_space(1))) void*)ga,
                (__attribute__((address_space(3))) void*)(&Alds[buf][lbase]), 16, 0, 0);
        }
#pragma unroll
        for (int p = 0; p < 2; ++p) {
            const int linear = p * 256 + tid;
            const int row = linear >> 2;
            const int seg = (linear & 3) ^ (row & 3);
            const int lbase = (p * 256 + w * 64) * 8;
            const __bf16* gb = W + (size_t)(nBase + row) * K + k0 + seg * 8;
            __builtin_amdgcn_global_load_lds(
                (const __attribute__((address_space(1))) void*)gb,
                (__attribute__((address_space(3))) void*)(&Blds[buf][lbase]), 16, 0, 0);
        }
    };

    stage(0, 0);
    int cur = 0;
    for (int k0 = 0; k0 < K; k0 += 32) {
        __syncthreads();
        if (k0 + 32 < K) stage(cur ^ 1, k0 + 32);

        bf16x8 af[2], bw[4];
#pragma unroll
        for (int i = 0; i < 2; ++i) {
            const int rowA = moff + i * 16 + c16;
            af[i] = *(const bf16x8*)&Alds[cur][rowA * 32 + ((quad ^ (rowA & 3)) << 3)];
        }
#pragma unroll
        for (int j = 0; j < 4; ++j) {
            const int rowB = noff + j * 16 + c16;
            bw[j] = *(const bf16x8*)&Blds[cur][rowB * 32 + ((quad ^ (rowB & 3)) << 3)];
        }
#pragma unroll
        for (int i = 0; i < 2; ++i)
#pragma unroll
            for (int j = 0; j < 4; ++j)
                acc[i][j] = mfma16(af[i], bw[j], acc[i][j]);
        cur ^= 1;
    }

#pragma unroll
    for (int j = 0; j < 4; ++j) {
        const int col = nBase + noff + j * 16 + c16;
        const float bv = HAS_BIAS ? bias[col] : 0.f;
#pragma unroll
        for (int i = 0; i < 2; ++i)
#pragma unroll
            for (int r = 0; r < 4; ++r) {
                const int row = mBase + moff + i * 16 + quad * 4 + r;
                stC(C, (size_t)row * N + col, acc[i][j][r] + bv);
            }
    }
}

// Split-K MFMA flash attention. Fixed-reference softmax (m=0, exp2 domain) makes
// partial accumulators LINEAR: O = (O_A+O_B)/(l_A+l_B) with no rescale.
// Tiles qt<16: one block, full range, writes ctx directly.
// Tiles qt>=16: two blocks (chunk ranges [0,half) and [half,qt+1)), each writes
// unnormalized fp32 O-partial + l-partial; combine kernel finishes.
// y mapping (dispatch order long-ish first): y<16 -> segA of qt=16+y;
// y in [16,32) -> segB of qt=y; y in [32,48) -> unsplit qt=47-y (len 16..1 last).
__global__ __launch_bounds__(256) void attn(
    const __bf16* __restrict__ qkv, __bf16* __restrict__ ctx,
    float* __restrict__ opart, float* __restrict__ lpart)
{
    __shared__ __bf16 Qs[64 * LDA];
    __shared__ __bf16 Ks[64 * LDA];
    __shared__ __bf16 Vs[64 * LDA];   // [d][k']
    __shared__ __bf16 Ps[64 * LDA];   // [q][k']

    const int tid  = threadIdx.x;
    const int lane = tid & 63;
    const int w    = tid >> 6;
    const int c16  = lane & 15;
    const int quad = lane >> 4;
    const int bh = blockIdx.x, b = bh >> 4, h = bh & 15;
    const int y  = blockIdx.y;

    int qt, c0, c1, seg;
    bool split;
    if (y < 16)      { qt = 16 + y; const int half = (qt + 2) >> 1; c0 = 0;    c1 = half;   split = true;  seg = 0; }
    else if (y < 32) { qt = y;      const int half = (qt + 2) >> 1; c0 = half; c1 = qt + 1; split = true;  seg = 1; }
    else             { qt = 47 - y; c0 = 0; c1 = qt + 1; split = false; seg = 0; }
    const int qBase = qt * 64;
    const int segIdx = split ? ((bh * 16 + (qt - 16)) * 2 + seg) : 0;

    const float QS = 0.125f * 1.4426950408889634f;  // (1/sqrt(64)) * log2(e)

    const int krow0 = tid >> 3;
    const int kd0   = (tid & 7) * 8;
    const int c16t = tid & 15;
    const int jh   = (tid >> 4) & 1;
    const int dblk = tid >> 5;

    const size_t rowB = (size_t)b * S_LEN;
    const __bf16* kp0 = qkv + (rowB + c0 * 64 + krow0) * 3072 + 1024 + h * 64 + kd0;
    const __bf16* kp1 = kp0 + (size_t)32 * 3072;
    const __bf16* vp0 = qkv + (rowB + c0 * 64 + 2 * jh * 16 + c16t) * 3072 + 2048 + h * 64 + dblk * 8;
    const __bf16* vp1 = vp0 + (size_t)16 * 3072;

    uint4 kr0 = *(const uint4*)kp0;
    uint4 kr1 = *(const uint4*)kp1;
    uint4 vr0 = *(const uint4*)vp0;
    uint4 vr1 = *(const uint4*)vp1;

    // stage Q (scaled)
#pragma unroll
    for (int p = 0; p < 2; ++p) {
        const int linear = p * 256 + tid;
        const int row = linear >> 3;
        const int d0 = (linear & 7) * 8;
        const __bf16* g = qkv + (rowB + qBase + row) * 3072 + h * 64 + d0;
        uint4 raw = *(const uint4*)g;
        const unsigned short* u = (const unsigned short*)&raw;
        unsigned short tmp[8];
#pragma unroll
        for (int jj = 0; jj < 8; ++jj) tmp[jj] = f2bf(bf2f(u[jj]) * QS);
        *(uint4*)&Qs[row * LDA + d0] = *(const uint4*)tmp;
    }
    __syncthreads();

    const bf16x8 aq0 = *(const bf16x8*)&Qs[(w * 16 + c16) * LDA + quad * 8];
    const bf16x8 aq1 = *(const bf16x8*)&Qs[(w * 16 + c16) * LDA + 32 + quad * 8];

    float l_r[4] = {0.f, 0.f, 0.f, 0.f};
    f32x4 acc_o[4];
#pragma unroll
    for (int j = 0; j < 4; ++j) acc_o[j] = (f32x4){0.f, 0.f, 0.f, 0.f};

    for (int cc = c0; cc < c1; ++cc) {
        *(uint4*)&Ks[krow0 * LDA + kd0]        = kr0;
        *(uint4*)&Ks[(krow0 + 32) * LDA + kd0] = kr1;
        {
            const unsigned short* e1 = (const unsigned short*)&vr0;
            const unsigned short* e2 = (const unsigned short*)&vr1;
#pragma unroll
            for (int d = 0; d < 8; ++d) {
                const unsigned pack = (unsigned)e1[d] | ((unsigned)e2[d] << 16);
                *(unsigned*)&Vs[(dblk * 8 + d) * LDA + c16t * 4 + 2 * jh] = pack;
            }
        }
        __syncthreads();

        if (cc + 1 < c1) {
            kp0 += (size_t)64 * 3072; kp1 += (size_t)64 * 3072;
            vp0 += (size_t)64 * 3072; vp1 += (size_t)64 * 3072;
            kr0 = *(const uint4*)kp0;
            kr1 = *(const uint4*)kp1;
            vr0 = *(const uint4*)vp0;
            vr1 = *(const uint4*)vp1;
        }

        f32x4 sc[4];
#pragma unroll
        for (int j = 0; j < 4; ++j) sc[j] = (f32x4){0.f, 0.f, 0.f, 0.f};
#pragma unroll
        for (int j = 0; j < 4; ++j) {
            bf16x8 bk0 = *(const bf16x8*)&Ks[(j * 16 + c16) * LDA + quad * 8];
            bf16x8 bk1 = *(const bf16x8*)&Ks[(j * 16 + c16) * LDA + 32 + quad * 8];
            sc[j] = mfma16(aq0, bk0, sc[j]);
            sc[j] = mfma16(aq1, bk1, sc[j]);
        }

        if (cc == qt) {   // diagonal chunk
#pragma unroll
            for (int j = 0; j < 4; ++j) {
                const int key = cc * 64 + j * 16 + c16;
#pragma unroll
                for (int r = 0; r < 4; ++r) {
                    const int q = qBase + w * 16 + quad * 4 + r;
                    if (key > q) sc[j][r] = -1e30f;
                }
            }
        }

        float p_[4][4];
#pragma unroll
        for (int j = 0; j < 4; ++j)
#pragma unroll
            for (int r = 0; r < 4; ++r)
                p_[j][r] = exp2f(sc[j][r]);
#pragma unroll
        for (int r = 0; r < 4; ++r)
            l_r[r] += (p_[0][r] + p_[1][r]) + (p_[2][r] + p_[3][r]);

#pragma unroll
        for (int r = 0; r < 4; ++r) {
            bf16x4 pb;
            pb[0] = (__bf16)p_[0][r]; pb[1] = (__bf16)p_[1][r];
            pb[2] = (__bf16)p_[2][r]; pb[3] = (__bf16)p_[3][r];
            *(bf16x4*)&Ps[(w * 16 + quad * 4 + r) * LDA + c16 * 4] = pb;
        }

        bf16x8 ap0 = *(const bf16x8*)&Ps[(w * 16 + c16) * LDA + quad * 8];
        bf16x8 ap1 = *(const bf16x8*)&Ps[(w * 16 + c16) * LDA + 32 + quad * 8];
#pragma unroll
        for (int j = 0; j < 4; ++j) {
            bf16x8 bv0 = *(const bf16x8*)&Vs[(j * 16 + c16) * LDA + quad * 8];
            bf16x8 bv1 = *(const bf16x8*)&Vs[(j * 16 + c16) * LDA + 32 + quad * 8];
            acc_o[j] = mfma16(ap0, bv0, acc_o[j]);
            acc_o[j] = mfma16(ap1, bv1, acc_o[j]);
        }
        __syncthreads();
    }

    if (!split) {
#pragma unroll
        for (int r = 0; r < 4; ++r) {
            float l = l_r[r];
            l += __shfl_xor(l, 1);
            l += __shfl_xor(l, 2);
            l += __shfl_xor(l, 4);
            l += __shfl_xor(l, 8);
            const float inv = 1.0f / l;
            const size_t rowO = (rowB + qBase + w * 16 + quad * 4 + r) * 1024 + h * 64;
#pragma unroll
            for (int j = 0; j < 4; ++j)
                ctx[rowO + j * 16 + c16] = (__bf16)(acc_o[j][r] * inv);
        }
    } else {
        float* ob = opart + (size_t)segIdx * 4096;
#pragma unroll
        for (int r = 0; r < 4; ++r) {
            float l = l_r[r];
            l += __shfl_xor(l, 1);
            l += __shfl_xor(l, 2);
            l += __shfl_xor(l, 4);
            l += __shfl_xor(l, 8);
            const int qrow = w * 16 + quad * 4 + r;
            if (c16 == 0) lpart[segIdx * 64 + qrow] = l;
#pragma unroll
            for (int j = 0; j < 4; ++j)
                ob[qrow * 64 + j * 16 + c16] = acc_o[j][r];
        }
    }
}

// Combine: ctx = (O_A + O_B) / (l_A + l_B) for the split tiles (qt 16..31).
__global__ __launch_bounds__(256) void attn_combine(
    const float* __restrict__ opart, const float* __restrict__ lpart,
    __bf16* __restrict__ ctx)
{
    const int blk = blockIdx.x;           // bh*16 + (qt-16)
    const int bh = blk >> 4, t = blk & 15;
    const int b = bh >> 4, h = bh & 15;
    const int qt = 16 + t;
    const int tid = threadIdx.x;
    const int q  = tid >> 2;
    const int d0 = (tid & 3) * 16;
    const int segA = blk * 2, segB = segA + 1;
    const float* oa = opart + (size_t)segA * 4096 + q * 64 + d0;
    const float* obp = opart + (size_t)segB * 4096 + q * 64 + d0;
    const float inv = 1.0f / (lpart[segA * 64 + q] + lpart[segB * 64 + q]);
    unsigned short outv[16];
#pragma unroll
    for (int i = 0; i < 4; ++i) {
        float4 a = ((const float4*)oa)[i];
        float4 c = ((const float4*)obp)[i];
        outv[4 * i + 0] = f2bf((a.x + c.x) * inv);
        outv[4 * i + 1] = f2bf((a.y + c.y) * inv);
        outv[4 * i + 2] = f2bf((a.z + c.z) * inv);
        outv[4 * i + 3] = f2bf((a.w + c.w) * inv);
    }
    __bf16* dst = ctx + ((size_t)(b * S_LEN + qt * 64 + q)) * 1024 + h * 64 + d0;
    *(uint4*)dst       = *(const uint4*)&outv[0];
    *(uint4*)(dst + 8) = *(const uint4*)&outv[8];
}

extern "C" void kernel_launch(void* const* d_in, const int* in_sizes, int n_in,
                              void* d_out, int out_size, void* d_ws, size_t ws_size,
                              hipStream_t stream) {
    const float* x      = (const float*)d_in[0];  // [2,2048,1024]
    const float* w_qkv  = (const float*)d_in[1];  // [3072,1024]
    const float* w_proj = (const float*)d_in[2];  // [1024,1024]
    const float* b_proj = (const float*)d_in[3];  // [1024]
    float* out = (float*)d_out;

    // workspace (same 40 MB footprint as R6):
    __bf16* qkvb = (__bf16*)d_ws;                         // [4096,3072]  25.2 MB
    __bf16* xb   = qkvb + (size_t)4096 * 3072;            // [4096,1024]   8.4 MB
    __bf16* wqb  = xb + (size_t)4096 * 1024;              // [3072,1024]   6.3 MB (dead after gemm1)
    __bf16* ctxb = xb;                                    // reuses xb
    __bf16* wpb  = wqb;                                   // w_proj bf16: first 2 MB of wqb region
    float*  lpart = (float*)(wqb + (size_t)1024 * 1024);  // 1024 segs x 64 = 256 KB, after wpb
    // O-partials: d_out used as scratch (1024 segs x 4096 f32 = 16.78 MB = sizeof(d_out));
    // proj GEMM overwrites every element of d_out afterwards.
    float* opart = out;

    const int M = B_SZ * S_LEN;  // 4096
    const int nx4 = 4096 * 1024 / 4, nq4 = 3072 * 1024 / 4, np4 = 1024 * 1024 / 4;

    // convert x + w_qkv to bf16
    f2b2_kernel<<<(nx4 + nq4 + 255) / 256, 256, 0, stream>>>(x, nx4, xb, w_qkv, nq4, wqb);

    // 1) QKV projection -> bf16
    gemm128<__bf16, 0><<<dim3(3072 / 128, M / 128), 256, 0, stream>>>(
        xb, wqb, nullptr, qkvb, M, 3072, 1024);

    // convert proj weights (wqb dead now)
    f2b_kernel<<<(np4 + 255) / 256, 256, 0, stream>>>(w_proj, wpb, np4);

    // 2) split-K causal flash attention (1536 blocks, <=16 chunks each)
    attn<<<dim3(B_SZ * NH, 48), 256, 0, stream>>>(qkvb, ctxb, opart, lpart);
    attn_combine<<<B_SZ * NH * 16, 256, 0, stream>>>(opart, lpart, ctxb);

    // 3) output projection + bias -> fp32
    gemm64<float, 1><<<dim3(1024 / 128, M / 64), 256, 0, stream>>>(
        ctxb, wpb, b_proj, out, M, 1024, 1024);
}